// Round 15
// baseline (703.933 us; speedup 1.0000x reference)
//
#include <hip/hip_runtime.h>

#define NN 50000
#define NE 400000
#define NFD 320
#define NB1 196   // ceil(NN/256) scan blocks

typedef short bf16x8 __attribute__((ext_vector_type(8)));
typedef float f32x4 __attribute__((ext_vector_type(4)));

#define MFMA16 __builtin_amdgcn_mfma_f32_16x16x32_bf16

__device__ __forceinline__ unsigned short f2bf(float f){
  unsigned int u = __float_as_uint(f);
  u += 0x7fffu + ((u >> 16) & 1u);
  return (unsigned short)(u >> 16);
}
__device__ __forceinline__ unsigned int cvt_pk_bf16(float lo, float hi){
  unsigned int r;
  asm("v_cvt_pk_bf16_f32 %0, %1, %2" : "=v"(r) : "v"(lo), "v"(hi));
  return r;
}
__device__ __forceinline__ float bflo(unsigned int q){ return __uint_as_float(q << 16); }
__device__ __forceinline__ float bfhi(unsigned int q){ return __uint_as_float(q & 0xffff0000u); }
__device__ __forceinline__ float rcp_fast(float x){
  float r;
  asm("v_rcp_f32 %0, %1" : "=v"(r) : "v"(x));
  return r;
}
__device__ __forceinline__ float silu_f(float x){
  return x * rcp_fast(1.f + __expf(-x));
}

// ---- weight-pack bodies (pure functions of idx) ----
__device__ __forceinline__ void pack_w_body(const float* __restrict__ W,
                                            unsigned short* __restrict__ P,
                                            int kstride, int KS, int idx){
  if (idx >= 20 * KS * 64) return;
  int lane = idx & 63;
  int t  = idx >> 6;
  int ks = t % KS;
  int ct = t / KS;
  const float* src = W + (size_t)(ct*16 + (lane & 15)) * kstride + ks*32 + 8*(lane >> 4);
  unsigned int q[4];
  #pragma unroll
  for (int j = 0; j < 4; j++) q[j] = cvt_pk_bf16(src[2*j], src[2*j+1]);
  *(uint4*)(P + (size_t)idx * 8) = make_uint4(q[0], q[1], q[2], q[3]);
}

__device__ __forceinline__ void pack_stack_body(const float* __restrict__ We1,
                                                unsigned short* __restrict__ P, int idx){
  if (idx >= 40 * 10 * 64) return;
  int lane = idx & 63;
  int t  = idx >> 6;
  int ks = t % 10;
  int ct = t / 10;                       // 0..39
  int o  = ct*16 + (lane & 15);          // 0..639
  int k  = ks*32 + 8*(lane >> 4);
  const float* src = (o < 320) ? (We1 + (size_t)o * 641 + k)
                               : (We1 + (size_t)(o - 320) * 641 + 320 + k);
  unsigned int q[4];
  #pragma unroll
  for (int j = 0; j < 4; j++) q[j] = cvt_pk_bf16(src[2*j], src[2*j+1]);
  *(uint4*)(P + (size_t)idx * 8) = make_uint4(q[0], q[1], q[2], q[3]);
}

// ---- merged prep kernel: pack + cinit + hist ----
#define PREP_PACK_B 176
#define PREP_CIN_B  293
#define PREP_HIST_B 782
__global__ void __launch_bounds__(512)
prep_k(const float* __restrict__ We2, const float* __restrict__ Wc1,
       const float* __restrict__ Wn1, const float* __restrict__ Wn2,
       const float* __restrict__ We1,
       unsigned short* __restrict__ We2p, unsigned short* __restrict__ Wc1p,
       unsigned short* __restrict__ Wn1p, unsigned short* __restrict__ Wn2p,
       unsigned short* __restrict__ Wsp, float* __restrict__ we1l,
       const float* __restrict__ coord, float* __restrict__ outc,
       const int* __restrict__ ei, int* __restrict__ cnt){
  int b = blockIdx.x;
  int tid = threadIdx.x;
  if (b < PREP_PACK_B){
    int idx = b*512 + tid;
    if (idx < 12800)       pack_w_body(We2, We2p, 320, 10, idx);
    else if (idx < 25600)  pack_w_body(Wc1, Wc1p, 320, 10, idx - 12800);
    else if (idx < 51200)  pack_w_body(Wn1, Wn1p, 640, 20, idx - 25600);
    else if (idx < 64000)  pack_w_body(Wn2, Wn2p, 320, 10, idx - 51200);
    else if (idx < 89600)  pack_stack_body(We1, Wsp, idx - 64000);
    else if (idx < 89920){
      int o = idx - 89600;
      we1l[o] = We1[(size_t)o * 641 + 640];
    }
  } else if (b < PREP_PACK_B + PREP_CIN_B){
    int i = (b - PREP_PACK_B)*512 + tid;
    if (i < NN*3) outc[i] = coord[i];
  } else {
    int e = (b - PREP_PACK_B - PREP_CIN_B)*512 + tid;
    if (e < NE) atomicAdd(&cnt[ei[e]], 1);
  }
}

__global__ void scan1(const int* __restrict__ cnt, int* __restrict__ cur,
                      int* __restrict__ bsum){
  __shared__ int sh[256];
  int tid = threadIdx.x;
  int i = blockIdx.x * 256 + tid;
  int v = (i < NN) ? cnt[i] : 0;
  sh[tid] = v;
  __syncthreads();
  for (int d = 1; d < 256; d <<= 1){
    int u = (tid >= d) ? sh[tid - d] : 0;
    __syncthreads();
    sh[tid] += u;
    __syncthreads();
  }
  if (i < NN) cur[i] = sh[tid] - v;            // exclusive within block
  if (tid == 255) bsum[blockIdx.x] = sh[255];  // block total
}

__global__ void scan2(int* __restrict__ bsum){
  __shared__ int sh[256];
  int tid = threadIdx.x;
  int v = (tid < NB1) ? bsum[tid] : 0;
  sh[tid] = v;
  __syncthreads();
  for (int d = 1; d < 256; d <<= 1){
    int u = (tid >= d) ? sh[tid - d] : 0;
    __syncthreads();
    sh[tid] += u;
    __syncthreads();
  }
  if (tid < NB1) bsum[tid] = sh[tid] - v;      // exclusive block offsets
}

__global__ void scan3(int* __restrict__ cur, const int* __restrict__ bsum){
  int i = blockIdx.x * 256 + threadIdx.x;
  if (i < NN) cur[i] += bsum[blockIdx.x];
}

// ---- gemm5: 2 row-tiles x 5 col-tiles, unrolled, depth-2 B prefetch ----
__device__ __forceinline__ void gemm5(const unsigned short* __restrict__ s,
                                      const unsigned short* __restrict__ wp,
                                      int arow0, int arow1, int kl,
                                      int fragbase, int KST, int lane, f32x4 (&acc)[2][5]){
  const unsigned short* wl0 = wp + (size_t)fragbase * 512 + (size_t)lane * 8;
  bf16x8 b0[5], b1[5];
  #pragma unroll
  for (int t = 0; t < 5; t++) b0[t] = *(const bf16x8*)(wl0 + (t*KST + 0)*512);
  #pragma unroll
  for (int t = 0; t < 5; t++) b1[t] = *(const bf16x8*)(wl0 + (t*KST + 1)*512);
  #pragma unroll
  for (int ks = 0; ks < 10; ks++){
    bf16x8 a0 = *(const bf16x8*)(s + arow0*328 + ks*32 + kl);
    bf16x8 a1 = *(const bf16x8*)(s + arow1*328 + ks*32 + kl);
    bf16x8 cur[5];
    #pragma unroll
    for (int t = 0; t < 5; t++) cur[t] = (ks & 1) ? b1[t] : b0[t];
    if (ks < 8){
      #pragma unroll
      for (int t = 0; t < 5; t++){
        bf16x8 nv = *(const bf16x8*)(wl0 + (t*KST + ks + 2)*512);
        if (ks & 1) b1[t] = nv; else b0[t] = nv;
      }
    }
    #pragma unroll
    for (int t = 0; t < 5; t++){
      acc[0][t] = MFMA16(a0, cur[t], acc[0][t], 0, 0, 0);
      acc[1][t] = MFMA16(a1, cur[t], acc[1][t], 0, 0, 0);
    }
  }
}

// ---- merged scatter (blocks 0..781) + pre_gemm (blocks 782..2344) ----
#define SP_SCAT_B 782
__global__ void __launch_bounds__(512, 4)
scat_pre(const int* __restrict__ ei, int* __restrict__ cur, int* __restrict__ perm,
         const float* __restrict__ h, const unsigned short* __restrict__ Wsp,
         const float* __restrict__ be1, unsigned short* __restrict__ P){
  if (blockIdx.x < SP_SCAT_B){
    int e = blockIdx.x * 512 + threadIdx.x;
    if (e < NE){
      int p = atomicAdd(&cur[ei[e]], 1);
      perm[p] = e;
    }
    return;
  }
  // ---- pre_gemm body ----
  __shared__ __align__(16) unsigned short s_h[32*328];

  const int tid  = threadIdx.x;
  const int lane = tid & 63;
  const int ch   = tid >> 6;      // 0..7 -> cols ch*80..+79 of 640
  const int n0   = (blockIdx.x - SP_SCAT_B) * 32;

  const int arow0 = (lane & 15);
  const int arow1 = 16 + (lane & 15);
  const int kl = 8 * (lane >> 4);
  const int rb = (lane >> 4) * 4;

  // stage h (f32 -> bf16): 32 rows x 80 float4
  #pragma unroll
  for (int i = 0; i < 5; i++){
    int idx = tid + i*512;
    int r = idx / 80;
    int c = idx - r*80;
    int node = n0 + r;
    float4 v = (node < NN) ? *(const float4*)(h + (size_t)node*NFD + c*4)
                           : make_float4(0,0,0,0);
    *(uint2*)(s_h + r*328 + c*4) = make_uint2(cvt_pk_bf16(v.x, v.y), cvt_pk_bf16(v.z, v.w));
  }
  __syncthreads();

  f32x4 acc[2][5];
  #pragma unroll
  for (int rt = 0; rt < 2; rt++)
    #pragma unroll
    for (int t = 0; t < 5; t++) acc[rt][t] = {0.f,0.f,0.f,0.f};

  gemm5(s_h, Wsp, arow0, arow1, kl, ch*50, 10, lane, acc);

  #pragma unroll
  for (int rt = 0; rt < 2; rt++){
    #pragma unroll
    for (int t = 0; t < 5; t++){
      int o = (ch*5 + t)*16 + (lane & 15);
      float bb = (o < 320) ? be1[o] : 0.f;   // fold edge-MLP bias into P_r
      #pragma unroll
      for (int r = 0; r < 4; r++){
        int node = n0 + rt*16 + rb + r;
        if (node < NN) P[(size_t)node*640 + o] = f2bf(acc[rt][t][r] + bb);
      }
    }
  }
}

// ---------------- edge kernel: 2-group software pipeline (64 edges/block, 256 thr) -----
// Groups g0 (edges 0..31) and g1 (32..63) interleave phases:
// B0+issue-gather1 | C0-gemm (gather1 in flight) | m2_0 + B1-finish | D0 + C1 |
// m2_1 + E0 | D1 | E1.  7 barriers per 64 edges (vs 10), gather1 hidden under MFMA.
__global__ void __launch_bounds__(256, 3)
edge_kernel(const unsigned short* __restrict__ Pbf, const float* __restrict__ coord,
            const int* __restrict__ ei, const int* __restrict__ perm,
            const float* __restrict__ we1l,
            const unsigned short* __restrict__ We2p, const float* __restrict__ be2,
            const unsigned short* __restrict__ Wc1p, const float* __restrict__ bc1,
            const float* __restrict__ Wc2,
            unsigned short* __restrict__ agg, float* __restrict__ cacc)
{
  __shared__ __align__(16) unsigned short s_b0[32*328]; // g0: m1 then m2
  __shared__ __align__(16) unsigned short s_b1[32*328]; // g1: m1 then m2
  __shared__ float4 s_cd[64];
  __shared__ int s_row[64];
  __shared__ int s_col[64];
  __shared__ float s_w[64];

  const int tid  = threadIdx.x;
  const int lane = tid & 63;
  const int ch   = tid >> 6;     // 0..3 = column chunk (80 cols)
  const int e0   = blockIdx.x * 64;

  // ---- phase A: both groups' edge meta ----
  if (tid < 64){
    int e = perm[e0 + tid];
    int r = ei[e];
    int c = ei[NE + e];
    s_row[tid] = r; s_col[tid] = c;
    s_w[tid] = 0.f;
    float dx = coord[r*3+0] - coord[c*3+0];
    float dy = coord[r*3+1] - coord[c*3+1];
    float dz = coord[r*3+2] - coord[c*3+2];
    float rad = dx*dx + dy*dy + dz*dz;
    float inv = 1.f / (sqrtf(rad) + 1e-8f);
    s_cd[tid] = make_float4(dx*inv, dy*inv, dz*inv, rad);
  }
  __syncthreads();                               // [1]

  const int arow0 = (lane & 15);
  const int arow1 = 16 + (lane & 15);
  const int kl = 8 * (lane >> 4);
  const int rb = (lane >> 4) * 4;

  // per-thread gather geometry (same for both groups)
  const int gr = tid / 40;        // 0..6 base row (with i*256 stride -> rows 0..31)
  // (indexing below recomputes per i to match R9 layout)

  uint4 PR1[5], PC1[5];           // group-1 gather results, live across C0 gemm

  // ---- B0: gather+silu -> s_b0 ; issue gather for g1 ----
  #pragma unroll
  for (int i = 0; i < 5; i++){
    int idx = tid + i*256;
    int r = idx / 40;
    int c = idx - r*40;
    uint4 pr = *(const uint4*)(Pbf + (size_t)s_row[r]*640 + c*8);
    uint4 pc = *(const uint4*)(Pbf + (size_t)s_col[r]*640 + 320 + c*8);
    // issue g1 loads early (consumed after C0 gemm)
    PR1[i] = *(const uint4*)(Pbf + (size_t)s_row[32 + r]*640 + c*8);
    PC1[i] = *(const uint4*)(Pbf + (size_t)s_col[32 + r]*640 + 320 + c*8);
    float4 wA = *(const float4*)(we1l + c*8);
    float4 wB = *(const float4*)(we1l + c*8 + 4);
    float rad = s_cd[r].w;
    float v0 = silu_f(bflo(pr.x) + bflo(pc.x) + rad*wA.x);
    float v1 = silu_f(bfhi(pr.x) + bfhi(pc.x) + rad*wA.y);
    float v2 = silu_f(bflo(pr.y) + bflo(pc.y) + rad*wA.z);
    float v3 = silu_f(bfhi(pr.y) + bfhi(pc.y) + rad*wA.w);
    float v4 = silu_f(bflo(pr.z) + bflo(pc.z) + rad*wB.x);
    float v5 = silu_f(bfhi(pr.z) + bfhi(pc.z) + rad*wB.y);
    float v6 = silu_f(bflo(pr.w) + bflo(pc.w) + rad*wB.z);
    float v7 = silu_f(bfhi(pr.w) + bfhi(pc.w) + rad*wB.w);
    uint4 q;
    q.x = cvt_pk_bf16(v0, v1);
    q.y = cvt_pk_bf16(v2, v3);
    q.z = cvt_pk_bf16(v4, v5);
    q.w = cvt_pk_bf16(v6, v7);
    *(uint4*)(s_b0 + r*328 + c*8) = q;
  }
  __syncthreads();                               // [2] m1_0 ready

  f32x4 acc[2][5];

  // ---- C0: m2_0 gemm (g1 gathers in flight underneath) ----
  #pragma unroll
  for (int rt = 0; rt < 2; rt++)
    #pragma unroll
    for (int t = 0; t < 5; t++) acc[rt][t] = {0.f,0.f,0.f,0.f};
  gemm5(s_b0, We2p, arow0, arow1, kl, ch*50, 10, lane, acc);
  __syncthreads();                               // [3] all reads of m1_0 done
  #pragma unroll
  for (int t = 0; t < 5; t++){
    int o = (ch*5 + t)*16 + (lane & 15);
    float bb = be2[o];
    #pragma unroll
    for (int r = 0; r < 4; r++){
      float v0 = silu_f(acc[0][t][r] + bb);
      float v1 = silu_f(acc[1][t][r] + bb);
      unsigned int q = cvt_pk_bf16(v0, v1);
      int er = rb + r;
      s_b0[er*328 + o] = (unsigned short)q;
      s_b0[(er+16)*328 + o] = (unsigned short)(q >> 16);
    }
  }

  // ---- B1-finish: silu on gathered regs -> s_b1 ----
  #pragma unroll
  for (int i = 0; i < 5; i++){
    int idx = tid + i*256;
    int r = idx / 40;
    int c = idx - r*40;
    uint4 pr = PR1[i];
    uint4 pc = PC1[i];
    float4 wA = *(const float4*)(we1l + c*8);
    float4 wB = *(const float4*)(we1l + c*8 + 4);
    float rad = s_cd[32 + r].w;
    float v0 = silu_f(bflo(pr.x) + bflo(pc.x) + rad*wA.x);
    float v1 = silu_f(bfhi(pr.x) + bfhi(pc.x) + rad*wA.y);
    float v2 = silu_f(bflo(pr.y) + bflo(pc.y) + rad*wA.z);
    float v3 = silu_f(bfhi(pr.y) + bfhi(pc.y) + rad*wA.w);
    float v4 = silu_f(bflo(pr.z) + bflo(pc.z) + rad*wB.x);
    float v5 = silu_f(bfhi(pr.z) + bfhi(pc.z) + rad*wB.y);
    float v6 = silu_f(bflo(pr.w) + bflo(pc.w) + rad*wB.z);
    float v7 = silu_f(bfhi(pr.w) + bfhi(pc.w) + rad*wB.w);
    uint4 q;
    q.x = cvt_pk_bf16(v0, v1);
    q.y = cvt_pk_bf16(v2, v3);
    q.z = cvt_pk_bf16(v4, v5);
    q.w = cvt_pk_bf16(v6, v7);
    *(uint4*)(s_b1 + r*328 + c*8) = q;
  }
  __syncthreads();                               // [4] m2_0 + m1_1 ready

  // ---- D0: c1_0 gemm + fused dot -> s_w[0..31] ----
  #pragma unroll
  for (int rt = 0; rt < 2; rt++)
    #pragma unroll
    for (int t = 0; t < 5; t++) acc[rt][t] = {0.f,0.f,0.f,0.f};
  gemm5(s_b0, Wc1p, arow0, arow1, kl, ch*50, 10, lane, acc);
  {
    float part[2][4];
    #pragma unroll
    for (int rt = 0; rt < 2; rt++)
      #pragma unroll
      for (int r = 0; r < 4; r++) part[rt][r] = 0.f;
    #pragma unroll
    for (int t = 0; t < 5; t++){
      int o = (ch*5 + t)*16 + (lane & 15);
      float bb = bc1[o];
      float wc = Wc2[o];
      #pragma unroll
      for (int rt = 0; rt < 2; rt++)
        #pragma unroll
        for (int r = 0; r < 4; r++)
          part[rt][r] = fmaf(silu_f(acc[rt][t][r] + bb), wc, part[rt][r]);
    }
    #pragma unroll
    for (int rt = 0; rt < 2; rt++)
      #pragma unroll
      for (int r = 0; r < 4; r++){
        float p = part[rt][r];
        p += __shfl_xor(p, 1);
        p += __shfl_xor(p, 2);
        p += __shfl_xor(p, 4);
        p += __shfl_xor(p, 8);
        if ((lane & 15) == 0)
          atomicAdd(&s_w[rt*16 + (lane >> 4)*4 + r], p);
      }
  }

  // ---- C1: m2_1 gemm (reuses acc after D0 done with it) ----
  #pragma unroll
  for (int rt = 0; rt < 2; rt++)
    #pragma unroll
    for (int t = 0; t < 5; t++) acc[rt][t] = {0.f,0.f,0.f,0.f};
  gemm5(s_b1, We2p, arow0, arow1, kl, ch*50, 10, lane, acc);
  __syncthreads();                               // [5] C1 reads done; s_w[0..31] done
  #pragma unroll
  for (int t = 0; t < 5; t++){
    int o = (ch*5 + t)*16 + (lane & 15);
    float bb = be2[o];
    #pragma unroll
    for (int r = 0; r < 4; r++){
      float v0 = silu_f(acc[0][t][r] + bb);
      float v1 = silu_f(acc[1][t][r] + bb);
      unsigned int q = cvt_pk_bf16(v0, v1);
      int er = rb + r;
      s_b1[er*328 + o] = (unsigned short)q;
      s_b1[(er+16)*328 + o] = (unsigned short)(q >> 16);
    }
  }

  // ---- E0: segment reduce m2_0 -> agg; coord scatter g0 ----
  if (tid < 160){
    int p = tid;
    float a0 = 0.f, a1 = 0.f;
    #pragma unroll
    for (int e = 0; e < 32; e++){
      unsigned int q = *(const unsigned int*)(s_b0 + e*328 + p*2);
      a0 += bflo(q); a1 += bfhi(q);
      if (e == 31 || s_row[e+1] != s_row[e]){
        unsigned int val = cvt_pk_bf16(a0, a1);
        unsigned short* dst = agg + (size_t)s_row[e]*NFD + p*2;
        asm volatile("global_atomic_pk_add_bf16 %0, %1, off" :: "v"(dst), "v"(val) : "memory");
        a0 = 0.f; a1 = 0.f;
      }
    }
  }
  if (tid >= 192 && tid < 195){
    int d = tid - 192;
    float a = 0.f;
    #pragma unroll
    for (int e = 0; e < 32; e++){
      float cdc = (d == 0) ? s_cd[e].x : (d == 1) ? s_cd[e].y : s_cd[e].z;
      a += cdc * s_w[e];
      if (e == 31 || s_row[e+1] != s_row[e]){
        atomicAdd(cacc + (size_t)s_row[e]*3 + d, a);
        a = 0.f;
      }
    }
  }
  __syncthreads();                               // [6] m2_1 ready

  // ---- D1: c1_1 gemm + fused dot -> s_w[32..63] ----
  #pragma unroll
  for (int rt = 0; rt < 2; rt++)
    #pragma unroll
    for (int t = 0; t < 5; t++) acc[rt][t] = {0.f,0.f,0.f,0.f};
  gemm5(s_b1, Wc1p, arow0, arow1, kl, ch*50, 10, lane, acc);
  {
    float part[2][4];
    #pragma unroll
    for (int rt = 0; rt < 2; rt++)
      #pragma unroll
      for (int r = 0; r < 4; r++) part[rt][r] = 0.f;
    #pragma unroll
    for (int t = 0; t < 5; t++){
      int o = (ch*5 + t)*16 + (lane & 15);
      float bb = bc1[o];
      float wc = Wc2[o];
      #pragma unroll
      for (int rt = 0; rt < 2; rt++)
        #pragma unroll
        for (int r = 0; r < 4; r++)
          part[rt][r] = fmaf(silu_f(acc[rt][t][r] + bb), wc, part[rt][r]);
    }
    #pragma unroll
    for (int rt = 0; rt < 2; rt++)
      #pragma unroll
      for (int r = 0; r < 4; r++){
        float p = part[rt][r];
        p += __shfl_xor(p, 1);
        p += __shfl_xor(p, 2);
        p += __shfl_xor(p, 4);
        p += __shfl_xor(p, 8);
        if ((lane & 15) == 0)
          atomicAdd(&s_w[32 + rt*16 + (lane >> 4)*4 + r], p);
      }
  }
  __syncthreads();                               // [7] s_w[32..63] done

  // ---- E1: segment reduce m2_1 -> agg; coord scatter g1 ----
  if (tid < 160){
    int p = tid;
    float a0 = 0.f, a1 = 0.f;
    #pragma unroll
    for (int k = 0; k < 32; k++){
      int e = 32 + k;
      unsigned int q = *(const unsigned int*)(s_b1 + k*328 + p*2);
      a0 += bflo(q); a1 += bfhi(q);
      if (k == 31 || s_row[e+1] != s_row[e]){
        unsigned int val = cvt_pk_bf16(a0, a1);
        unsigned short* dst = agg + (size_t)s_row[e]*NFD + p*2;
        asm volatile("global_atomic_pk_add_bf16 %0, %1, off" :: "v"(dst), "v"(val) : "memory");
        a0 = 0.f; a1 = 0.f;
      }
    }
  }
  if (tid >= 192 && tid < 195){
    int d = tid - 192;
    float a = 0.f;
    #pragma unroll
    for (int k = 0; k < 32; k++){
      int e = 32 + k;
      float cdc = (d == 0) ? s_cd[e].x : (d == 1) ? s_cd[e].y : s_cd[e].z;
      a += cdc * s_w[e];
      if (k == 31 || s_row[e+1] != s_row[e]){
        atomicAdd(cacc + (size_t)s_row[e]*3 + d, a);
        a = 0.f;
      }
    }
  }
}

// ---------------- node kernel: 64 nodes/block, 512 threads (8 waves, B-sharing) --------
__global__ void __launch_bounds__(512, 4)
node_kernel(const float* __restrict__ h, const unsigned short* __restrict__ agg,
            const unsigned short* __restrict__ Wn1p, const float* __restrict__ bn1,
            const unsigned short* __restrict__ Wn2p, const float* __restrict__ bn2,
            float* __restrict__ hout)
{
  __shared__ __align__(16) unsigned short s_b[64*328];

  const int tid  = threadIdx.x;
  const int lane = tid & 63;
  const int wv   = tid >> 6;     // 0..7
  const int ch   = wv & 3;       // column chunk (80 cols)
  const int rh   = wv >> 2;      // row half (32 nodes each)
  const int n0   = blockIdx.x * 64;

  const int arow0 = rh*32 + (lane & 15);
  const int arow1 = rh*32 + 16 + (lane & 15);
  const int kl = 8 * (lane >> 4);
  const int rb = (lane >> 4) * 4;

  f32x4 acc[2][5];
  #pragma unroll
  for (int rt = 0; rt < 2; rt++)
    #pragma unroll
    for (int t = 0; t < 5; t++) acc[rt][t] = {0.f,0.f,0.f,0.f};

  // ---- stage h (f32 -> bf16): 64 rows x 80 float4 ----
  #pragma unroll
  for (int i = 0; i < 10; i++){
    int idx = tid + i*512;
    int r = idx / 80;
    int c = idx - r*80;
    int node = n0 + r;
    float4 v = (node < NN) ? *(const float4*)(h + (size_t)node*NFD + c*4)
                           : make_float4(0,0,0,0);
    *(uint2*)(s_b + r*328 + c*4) = make_uint2(cvt_pk_bf16(v.x, v.y), cvt_pk_bf16(v.z, v.w));
  }
  __syncthreads();

  // ---- n1 half0 (h part): ks 0..9, Wn1p tiles have KST=20 ----
  gemm5(s_b, Wn1p, arow0, arow1, kl, ch*100, 20, lane, acc);
  __syncthreads();

  // ---- stage agg (bf16 copy, overwrites h tile): 64 rows x 40 uint4 ----
  #pragma unroll
  for (int i = 0; i < 5; i++){
    int idx = tid + i*512;
    int r = idx / 40;
    int c = idx - r*40;
    int node = n0 + r;
    uint4 v = (node < NN) ? *(const uint4*)(agg + (size_t)node*NFD + c*8)
                          : make_uint4(0,0,0,0);
    *(uint4*)(s_b + r*328 + c*8) = v;
  }
  __syncthreads();

  // ---- n1 half1 (agg part): ks 10..19 ----
  gemm5(s_b, Wn1p, arow0, arow1, kl, ch*100 + 10, 20, lane, acc);
  __syncthreads();               // all waves done reading agg

  // ---- hid = silu(n1) -> s_b (overwrite, d16hi trick) ----
  #pragma unroll
  for (int t = 0; t < 5; t++){
    int o = (ch*5 + t)*16 + (lane & 15);
    float bb = bn1[o];
    #pragma unroll
    for (int r = 0; r < 4; r++){
      float v0 = silu_f(acc[0][t][r] + bb);
      float v1 = silu_f(acc[1][t][r] + bb);
      unsigned int q = cvt_pk_bf16(v0, v1);
      int er = rh*32 + rb + r;
      s_b[er*328 + o] = (unsigned short)q;
      s_b[(er+16)*328 + o] = (unsigned short)(q >> 16);
    }
  }
  __syncthreads();

  // ---- n2: out = hid @ Wn2^T + bn2 + h (residual) ----
  #pragma unroll
  for (int rt = 0; rt < 2; rt++)
    #pragma unroll
    for (int t = 0; t < 5; t++) acc[rt][t] = {0.f,0.f,0.f,0.f};
  gemm5(s_b, Wn2p, arow0, arow1, kl, ch*50, 10, lane, acc);
  #pragma unroll
  for (int t = 0; t < 5; t++){
    int o = (ch*5 + t)*16 + (lane & 15);
    float bb = bn2[o];
    #pragma unroll
    for (int r = 0; r < 4; r++){
      int node0 = n0 + rh*32 + rb + r;
      int node1 = node0 + 16;
      if (node0 < NN)
        hout[(size_t)node0*NFD + o] = h[(size_t)node0*NFD + o] + acc[0][t][r] + bb;
      if (node1 < NN)
        hout[(size_t)node1*NFD + o] = h[(size_t)node1*NFD + o] + acc[1][t][r] + bb;
    }
  }
}

extern "C" void kernel_launch(void* const* d_in, const int* in_sizes, int n_in,
                              void* d_out, int out_size, void* d_ws, size_t ws_size,
                              hipStream_t stream){
  const float* h     = (const float*)d_in[0];
  const float* coord = (const float*)d_in[1];
  const int*   ei    = (const int*)d_in[2];
  const float* We1 = (const float*)d_in[3];
  const float* be1 = (const float*)d_in[4];
  const float* We2 = (const float*)d_in[5];
  const float* be2 = (const float*)d_in[6];
  const float* Wn1 = (const float*)d_in[7];
  const float* bn1 = (const float*)d_in[8];
  const float* Wn2 = (const float*)d_in[9];
  const float* bn2 = (const float*)d_in[10];
  const float* Wc1 = (const float*)d_in[11];
  const float* bc1 = (const float*)d_in[12];
  const float* Wc2 = (const float*)d_in[13];

  char* ws = (char*)d_ws;
  unsigned short* We2p = (unsigned short*)(ws);             // 204800
  unsigned short* Wc1p = (unsigned short*)(ws + 204800);    // 204800
  unsigned short* Wn1p = (unsigned short*)(ws + 409600);    // 409600
  unsigned short* Wn2p = (unsigned short*)(ws + 819200);    // 204800
  unsigned short* Wsp  = (unsigned short*)(ws + 1024000);   // 409600
  float*          we1l = (float*)(ws + 1433600);            // 1280
  unsigned short* agg  = (unsigned short*)(ws + 1434880);   // 32,000,000
  int*            cnt  = (int*)(ws + 33434880);             // 200,000
  int*            cur  = (int*)(ws + 33634880);             // 200,000
  int*            perm = (int*)(ws + 33834880);             // 1,600,000
  int*            bsum = (int*)(ws + 35434880);             // 1,024

  float* hout = (float*)d_out;
  float* cout = hout + (size_t)NN * NFD;        // coord output region
  unsigned short* Pbf = (unsigned short*)d_out; // P in dead hout region (64 MB)

  hipMemsetAsync(agg, 0, (size_t)NN * NFD * 2, stream);
  hipMemsetAsync(cnt, 0, (size_t)NN * 4, stream);

  prep_k<<<PREP_PACK_B + PREP_CIN_B + PREP_HIST_B, 512, 0, stream>>>(
      We2, Wc1, Wn1, Wn2, We1, We2p, Wc1p, Wn1p, Wn2p, Wsp, we1l,
      coord, cout, ei, cnt);

  scan1<<<NB1, 256, 0, stream>>>(cnt, cur, bsum);
  scan2<<<1, 256, 0, stream>>>(bsum);
  scan3<<<NB1, 256, 0, stream>>>(cur, bsum);

  scat_pre<<<SP_SCAT_B + (NN + 31)/32, 512, 0, stream>>>(
      ei, cur, perm, h, Wsp, be1, Pbf);

  edge_kernel<<<NE/64, 256, 0, stream>>>(Pbf, coord, ei, perm, we1l,
                                         We2p, be2, Wc1p, bc1, Wc2, agg, cout);
  node_kernel<<<(NN + 63)/64, 512, 0, stream>>>(h, agg, Wn1p, bn1, Wn2p, bn2, hout);
}

// Round 16
// 533.525 us; speedup vs baseline: 1.3194x; 1.3194x over previous
//
#include <hip/hip_runtime.h>

#define NN 50000
#define NE 400000
#define NFD 320
#define NB1 196   // ceil(NN/256) scan blocks

typedef short bf16x8 __attribute__((ext_vector_type(8)));
typedef float f32x4 __attribute__((ext_vector_type(4)));

#define MFMA16 __builtin_amdgcn_mfma_f32_16x16x32_bf16

__device__ __forceinline__ unsigned short f2bf(float f){
  unsigned int u = __float_as_uint(f);
  u += 0x7fffu + ((u >> 16) & 1u);
  return (unsigned short)(u >> 16);
}
__device__ __forceinline__ unsigned int cvt_pk_bf16(float lo, float hi){
  unsigned int r;
  asm("v_cvt_pk_bf16_f32 %0, %1, %2" : "=v"(r) : "v"(lo), "v"(hi));
  return r;
}
__device__ __forceinline__ float bflo(unsigned int q){ return __uint_as_float(q << 16); }
__device__ __forceinline__ float bfhi(unsigned int q){ return __uint_as_float(q & 0xffff0000u); }
__device__ __forceinline__ float rcp_fast(float x){
  float r;
  asm("v_rcp_f32 %0, %1" : "=v"(r) : "v"(x));
  return r;
}
__device__ __forceinline__ float silu_f(float x){
  return x * rcp_fast(1.f + __expf(-x));
}

// ---- weight-pack bodies (pure functions of idx) ----
__device__ __forceinline__ void pack_w_body(const float* __restrict__ W,
                                            unsigned short* __restrict__ P,
                                            int kstride, int KS, int idx){
  if (idx >= 20 * KS * 64) return;
  int lane = idx & 63;
  int t  = idx >> 6;
  int ks = t % KS;
  int ct = t / KS;
  const float* src = W + (size_t)(ct*16 + (lane & 15)) * kstride + ks*32 + 8*(lane >> 4);
  unsigned int q[4];
  #pragma unroll
  for (int j = 0; j < 4; j++) q[j] = cvt_pk_bf16(src[2*j], src[2*j+1]);
  *(uint4*)(P + (size_t)idx * 8) = make_uint4(q[0], q[1], q[2], q[3]);
}

__device__ __forceinline__ void pack_stack_body(const float* __restrict__ We1,
                                                unsigned short* __restrict__ P, int idx){
  if (idx >= 40 * 10 * 64) return;
  int lane = idx & 63;
  int t  = idx >> 6;
  int ks = t % 10;
  int ct = t / 10;                       // 0..39
  int o  = ct*16 + (lane & 15);          // 0..639
  int k  = ks*32 + 8*(lane >> 4);
  const float* src = (o < 320) ? (We1 + (size_t)o * 641 + k)
                               : (We1 + (size_t)(o - 320) * 641 + 320 + k);
  unsigned int q[4];
  #pragma unroll
  for (int j = 0; j < 4; j++) q[j] = cvt_pk_bf16(src[2*j], src[2*j+1]);
  *(uint4*)(P + (size_t)idx * 8) = make_uint4(q[0], q[1], q[2], q[3]);
}

// ---- merged prep kernel: pack + cinit + hist ----
#define PREP_PACK_B 176   // 176*512 = 90112 >= 89920 pack items
#define PREP_CIN_B  293   // 293*512 = 150016 >= 150000
#define PREP_HIST_B 782   // 782*512 = 400384 >= 400000
__global__ void __launch_bounds__(512)
prep_k(const float* __restrict__ We2, const float* __restrict__ Wc1,
       const float* __restrict__ Wn1, const float* __restrict__ Wn2,
       const float* __restrict__ We1,
       unsigned short* __restrict__ We2p, unsigned short* __restrict__ Wc1p,
       unsigned short* __restrict__ Wn1p, unsigned short* __restrict__ Wn2p,
       unsigned short* __restrict__ Wsp, float* __restrict__ we1l,
       const float* __restrict__ coord, float* __restrict__ outc,
       const int* __restrict__ ei, int* __restrict__ cnt){
  int b = blockIdx.x;
  int tid = threadIdx.x;
  if (b < PREP_PACK_B){
    int idx = b*512 + tid;
    if (idx < 12800)       pack_w_body(We2, We2p, 320, 10, idx);
    else if (idx < 25600)  pack_w_body(Wc1, Wc1p, 320, 10, idx - 12800);
    else if (idx < 51200)  pack_w_body(Wn1, Wn1p, 640, 20, idx - 25600);
    else if (idx < 64000)  pack_w_body(Wn2, Wn2p, 320, 10, idx - 51200);
    else if (idx < 89600)  pack_stack_body(We1, Wsp, idx - 64000);
    else if (idx < 89920){
      int o = idx - 89600;
      we1l[o] = We1[(size_t)o * 641 + 640];
    }
  } else if (b < PREP_PACK_B + PREP_CIN_B){
    int i = (b - PREP_PACK_B)*512 + tid;
    if (i < NN*3) outc[i] = coord[i];
  } else {
    int e = (b - PREP_PACK_B - PREP_CIN_B)*512 + tid;
    if (e < NE) atomicAdd(&cnt[ei[e]], 1);
  }
}

__global__ void scan1(const int* __restrict__ cnt, int* __restrict__ cur,
                      int* __restrict__ bsum){
  __shared__ int sh[256];
  int tid = threadIdx.x;
  int i = blockIdx.x * 256 + tid;
  int v = (i < NN) ? cnt[i] : 0;
  sh[tid] = v;
  __syncthreads();
  for (int d = 1; d < 256; d <<= 1){
    int u = (tid >= d) ? sh[tid - d] : 0;
    __syncthreads();
    sh[tid] += u;
    __syncthreads();
  }
  if (i < NN) cur[i] = sh[tid] - v;            // exclusive within block
  if (tid == 255) bsum[blockIdx.x] = sh[255];  // block total
}

__global__ void scan2(int* __restrict__ bsum){
  __shared__ int sh[256];
  int tid = threadIdx.x;
  int v = (tid < NB1) ? bsum[tid] : 0;
  sh[tid] = v;
  __syncthreads();
  for (int d = 1; d < 256; d <<= 1){
    int u = (tid >= d) ? sh[tid - d] : 0;
    __syncthreads();
    sh[tid] += u;
    __syncthreads();
  }
  if (tid < NB1) bsum[tid] = sh[tid] - v;      // exclusive block offsets
}

__global__ void scan3(int* __restrict__ cur, const int* __restrict__ bsum){
  int i = blockIdx.x * 256 + threadIdx.x;
  if (i < NN) cur[i] += bsum[blockIdx.x];
}

// ---- gemm5: 2 row-tiles x 5 col-tiles, unrolled, depth-2 B prefetch ----
__device__ __forceinline__ void gemm5(const unsigned short* __restrict__ s,
                                      const unsigned short* __restrict__ wp,
                                      int arow0, int arow1, int kl,
                                      int fragbase, int KST, int lane, f32x4 (&acc)[2][5]){
  const unsigned short* wl0 = wp + (size_t)fragbase * 512 + (size_t)lane * 8;
  bf16x8 b0[5], b1[5];
  #pragma unroll
  for (int t = 0; t < 5; t++) b0[t] = *(const bf16x8*)(wl0 + (t*KST + 0)*512);
  #pragma unroll
  for (int t = 0; t < 5; t++) b1[t] = *(const bf16x8*)(wl0 + (t*KST + 1)*512);
  #pragma unroll
  for (int ks = 0; ks < 10; ks++){
    bf16x8 a0 = *(const bf16x8*)(s + arow0*328 + ks*32 + kl);
    bf16x8 a1 = *(const bf16x8*)(s + arow1*328 + ks*32 + kl);
    bf16x8 cur[5];
    #pragma unroll
    for (int t = 0; t < 5; t++) cur[t] = (ks & 1) ? b1[t] : b0[t];
    if (ks < 8){
      #pragma unroll
      for (int t = 0; t < 5; t++){
        bf16x8 nv = *(const bf16x8*)(wl0 + (t*KST + ks + 2)*512);
        if (ks & 1) b1[t] = nv; else b0[t] = nv;
      }
    }
    #pragma unroll
    for (int t = 0; t < 5; t++){
      acc[0][t] = MFMA16(a0, cur[t], acc[0][t], 0, 0, 0);
      acc[1][t] = MFMA16(a1, cur[t], acc[1][t], 0, 0, 0);
    }
  }
}

// ---- merged scatter (blocks 0..781) + pre_gemm (blocks 782..2344) ----
#define SP_SCAT_B 782
__global__ void __launch_bounds__(512, 4)
scat_pre(const int* __restrict__ ei, int* __restrict__ cur, int* __restrict__ perm,
         const float* __restrict__ h, const unsigned short* __restrict__ Wsp,
         const float* __restrict__ be1, unsigned short* __restrict__ P){
  if (blockIdx.x < SP_SCAT_B){
    int e = blockIdx.x * 512 + threadIdx.x;
    if (e < NE){
      int p = atomicAdd(&cur[ei[e]], 1);
      perm[p] = e;
    }
    return;
  }
  // ---- pre_gemm body ----
  __shared__ __align__(16) unsigned short s_h[32*328];

  const int tid  = threadIdx.x;
  const int lane = tid & 63;
  const int ch   = tid >> 6;      // 0..7 -> cols ch*80..+79 of 640
  const int n0   = (blockIdx.x - SP_SCAT_B) * 32;

  const int arow0 = (lane & 15);
  const int arow1 = 16 + (lane & 15);
  const int kl = 8 * (lane >> 4);
  const int rb = (lane >> 4) * 4;

  // stage h (f32 -> bf16): 32 rows x 80 float4
  #pragma unroll
  for (int i = 0; i < 5; i++){
    int idx = tid + i*512;
    int r = idx / 80;
    int c = idx - r*80;
    int node = n0 + r;
    float4 v = (node < NN) ? *(const float4*)(h + (size_t)node*NFD + c*4)
                           : make_float4(0,0,0,0);
    *(uint2*)(s_h + r*328 + c*4) = make_uint2(cvt_pk_bf16(v.x, v.y), cvt_pk_bf16(v.z, v.w));
  }
  __syncthreads();

  f32x4 acc[2][5];
  #pragma unroll
  for (int rt = 0; rt < 2; rt++)
    #pragma unroll
    for (int t = 0; t < 5; t++) acc[rt][t] = {0.f,0.f,0.f,0.f};

  gemm5(s_h, Wsp, arow0, arow1, kl, ch*50, 10, lane, acc);

  #pragma unroll
  for (int rt = 0; rt < 2; rt++){
    #pragma unroll
    for (int t = 0; t < 5; t++){
      int o = (ch*5 + t)*16 + (lane & 15);
      float bb = (o < 320) ? be1[o] : 0.f;   // fold edge-MLP bias into P_r
      #pragma unroll
      for (int r = 0; r < 4; r++){
        int node = n0 + rt*16 + rb + r;
        if (node < NN) P[(size_t)node*640 + o] = f2bf(acc[rt][t][r] + bb);
      }
    }
  }
}

// ---------------- edge kernel: 32 sorted edges/block, (256,5), XCD-swizzled ------------
#define EDGE_NWG (NE/32)          // 12500
#define SWZ_Q (EDGE_NWG/8)        // 1562
#define SWZ_R (EDGE_NWG%8)        // 4
__global__ void __launch_bounds__(256, 5)
edge_kernel(const unsigned short* __restrict__ Pbf, const float* __restrict__ coord,
            const int* __restrict__ ei, const int* __restrict__ perm,
            const float* __restrict__ we1l,
            const unsigned short* __restrict__ We2p, const float* __restrict__ be2,
            const unsigned short* __restrict__ Wc1p, const float* __restrict__ bc1,
            const float* __restrict__ Wc2,
            unsigned short* __restrict__ agg, float* __restrict__ cacc)
{
  __shared__ __align__(16) unsigned short s_b[32*328]; // m1, then m2
  __shared__ float4 s_cd[32];
  __shared__ int s_row[32];
  __shared__ int s_col[32];
  __shared__ float s_w[32];

  const int tid  = threadIdx.x;
  const int lane = tid & 63;
  const int ch   = tid >> 6;     // 0..3 = column chunk (80 cols)

  // bijective XCD swizzle: orig -> wgid so that consecutive wgid share an XCD chunk
  const int orig = blockIdx.x;
  const int xcd  = orig & 7;
  const int k    = orig >> 3;
  const int wgid = (xcd < SWZ_R ? xcd*(SWZ_Q+1) : SWZ_R*(SWZ_Q+1) + (xcd-SWZ_R)*SWZ_Q) + k;
  const int e0   = wgid * 32;

  // ---- phase A ----
  if (tid < 32){
    int e = perm[e0 + tid];
    int r = ei[e];
    int c = ei[NE + e];
    s_row[tid] = r; s_col[tid] = c;
    s_w[tid] = 0.f;
    float dx = coord[r*3+0] - coord[c*3+0];
    float dy = coord[r*3+1] - coord[c*3+1];
    float dz = coord[r*3+2] - coord[c*3+2];
    float rad = dx*dx + dy*dy + dz*dz;
    float inv = 1.f / (sqrtf(rad) + 1e-8f);
    s_cd[tid] = make_float4(dx*inv, dy*inv, dz*inv, rad);
  }
  __syncthreads();

  const int arow0 = (lane & 15);
  const int arow1 = 16 + (lane & 15);
  const int kl = 8 * (lane >> 4);
  const int rb = (lane >> 4) * 4;

  // ---- phase B: m1 = silu(P_r[row] + P_c[col] + rad*wl) -> s_b ----
  #pragma unroll
  for (int i = 0; i < 5; i++){
    int idx = tid + i*256;
    int r = idx / 40;
    int c = idx - r*40;
    uint4 pr = *(const uint4*)(Pbf + (size_t)s_row[r]*640 + c*8);
    uint4 pc = *(const uint4*)(Pbf + (size_t)s_col[r]*640 + 320 + c*8);
    float4 wA = *(const float4*)(we1l + c*8);
    float4 wB = *(const float4*)(we1l + c*8 + 4);
    float rad = s_cd[r].w;
    float v0 = silu_f(bflo(pr.x) + bflo(pc.x) + rad*wA.x);
    float v1 = silu_f(bfhi(pr.x) + bfhi(pc.x) + rad*wA.y);
    float v2 = silu_f(bflo(pr.y) + bflo(pc.y) + rad*wA.z);
    float v3 = silu_f(bfhi(pr.y) + bfhi(pc.y) + rad*wA.w);
    float v4 = silu_f(bflo(pr.z) + bflo(pc.z) + rad*wB.x);
    float v5 = silu_f(bfhi(pr.z) + bfhi(pc.z) + rad*wB.y);
    float v6 = silu_f(bflo(pr.w) + bflo(pc.w) + rad*wB.z);
    float v7 = silu_f(bfhi(pr.w) + bfhi(pc.w) + rad*wB.w);
    uint4 q;
    q.x = cvt_pk_bf16(v0, v1);
    q.y = cvt_pk_bf16(v2, v3);
    q.z = cvt_pk_bf16(v4, v5);
    q.w = cvt_pk_bf16(v6, v7);
    *(uint4*)(s_b + r*328 + c*8) = q;
  }
  __syncthreads();

  f32x4 acc[2][5];

  // ---- phase C: m2 = silu(m1 @ We2^T + be2), single-buffer overwrite ----
  #pragma unroll
  for (int rt = 0; rt < 2; rt++)
    #pragma unroll
    for (int t = 0; t < 5; t++) acc[rt][t] = {0.f,0.f,0.f,0.f};
  gemm5(s_b, We2p, arow0, arow1, kl, ch*50, 10, lane, acc);
  __syncthreads();               // all waves done reading m1
  #pragma unroll
  for (int t = 0; t < 5; t++){
    int o = (ch*5 + t)*16 + (lane & 15);
    float bb = be2[o];
    #pragma unroll
    for (int r = 0; r < 4; r++){
      float v0 = silu_f(acc[0][t][r] + bb);
      float v1 = silu_f(acc[1][t][r] + bb);
      unsigned int q = cvt_pk_bf16(v0, v1);
      int er = rb + r;
      s_b[er*328 + o] = (unsigned short)q;              // rt0 row
      s_b[(er+16)*328 + o] = (unsigned short)(q >> 16); // rt1 row (d16_hi)
    }
  }
  __syncthreads();

  // ---- phase D: c1 GEMM, fused silu + Wc2 dot (no LDS round-trip) ----
  #pragma unroll
  for (int rt = 0; rt < 2; rt++)
    #pragma unroll
    for (int t = 0; t < 5; t++) acc[rt][t] = {0.f,0.f,0.f,0.f};
  gemm5(s_b, Wc1p, arow0, arow1, kl, ch*50, 10, lane, acc);
  {
    float part[2][4];
    #pragma unroll
    for (int rt = 0; rt < 2; rt++)
      #pragma unroll
      for (int r = 0; r < 4; r++) part[rt][r] = 0.f;
    #pragma unroll
    for (int t = 0; t < 5; t++){
      int o = (ch*5 + t)*16 + (lane & 15);
      float bb = bc1[o];
      float wc = Wc2[o];
      #pragma unroll
      for (int rt = 0; rt < 2; rt++)
        #pragma unroll
        for (int r = 0; r < 4; r++)
          part[rt][r] = fmaf(silu_f(acc[rt][t][r] + bb), wc, part[rt][r]);
    }
    #pragma unroll
    for (int rt = 0; rt < 2; rt++)
      #pragma unroll
      for (int r = 0; r < 4; r++){
        float p = part[rt][r];
        p += __shfl_xor(p, 1);
        p += __shfl_xor(p, 2);
        p += __shfl_xor(p, 4);
        p += __shfl_xor(p, 8);
        if ((lane & 15) == 0)
          atomicAdd(&s_w[rt*16 + (lane >> 4)*4 + r], p);
      }
  }
  __syncthreads();               // s_w complete; m2 still intact in s_b

  // ---- phase E: segmented reduce of m2 -> agg; coord scatter ----
  if (tid < 160){
    int p = tid;
    float a0 = 0.f, a1 = 0.f;
    #pragma unroll
    for (int e = 0; e < 32; e++){
      unsigned int q = *(const unsigned int*)(s_b + e*328 + p*2);
      a0 += bflo(q); a1 += bfhi(q);
      if (e == 31 || s_row[e+1] != s_row[e]){
        unsigned int val = cvt_pk_bf16(a0, a1);
        unsigned short* dst = agg + (size_t)s_row[e]*NFD + p*2;
        asm volatile("global_atomic_pk_add_bf16 %0, %1, off" :: "v"(dst), "v"(val) : "memory");
        a0 = 0.f; a1 = 0.f;
      }
    }
  }
  if (tid >= 192 && tid < 195){
    int d = tid - 192;
    float a = 0.f;
    #pragma unroll
    for (int e = 0; e < 32; e++){
      float cdc = (d == 0) ? s_cd[e].x : (d == 1) ? s_cd[e].y : s_cd[e].z;
      a += cdc * s_w[e];
      if (e == 31 || s_row[e+1] != s_row[e]){
        atomicAdd(cacc + (size_t)s_row[e]*3 + d, a);
        a = 0.f;
      }
    }
  }
}

// ---------------- node kernel: 64 nodes/block, 512 threads (8 waves, B-sharing) --------
__global__ void __launch_bounds__(512, 4)
node_kernel(const float* __restrict__ h, const unsigned short* __restrict__ agg,
            const unsigned short* __restrict__ Wn1p, const float* __restrict__ bn1,
            const unsigned short* __restrict__ Wn2p, const float* __restrict__ bn2,
            float* __restrict__ hout)
{
  __shared__ __align__(16) unsigned short s_b[64*328];

  const int tid  = threadIdx.x;
  const int lane = tid & 63;
  const int wv   = tid >> 6;     // 0..7
  const int ch   = wv & 3;       // column chunk (80 cols)
  const int rh   = wv >> 2;      // row half (32 nodes each)
  const int n0   = blockIdx.x * 64;

  const int arow0 = rh*32 + (lane & 15);
  const int arow1 = rh*32 + 16 + (lane & 15);
  const int kl = 8 * (lane >> 4);
  const int rb = (lane >> 4) * 4;

  f32x4 acc[2][5];
  #pragma unroll
  for (int rt = 0; rt < 2; rt++)
    #pragma unroll
    for (int t = 0; t < 5; t++) acc[rt][t] = {0.f,0.f,0.f,0.f};

  // ---- stage h (f32 -> bf16): 64 rows x 80 float4 ----
  #pragma unroll
  for (int i = 0; i < 10; i++){
    int idx = tid + i*512;
    int r = idx / 80;
    int c = idx - r*80;
    int node = n0 + r;
    float4 v = (node < NN) ? *(const float4*)(h + (size_t)node*NFD + c*4)
                           : make_float4(0,0,0,0);
    *(uint2*)(s_b + r*328 + c*4) = make_uint2(cvt_pk_bf16(v.x, v.y), cvt_pk_bf16(v.z, v.w));
  }
  __syncthreads();

  // ---- n1 half0 (h part): ks 0..9, Wn1p tiles have KST=20 ----
  gemm5(s_b, Wn1p, arow0, arow1, kl, ch*100, 20, lane, acc);
  __syncthreads();

  // ---- stage agg (bf16 copy, overwrites h tile): 64 rows x 40 uint4 ----
  #pragma unroll
  for (int i = 0; i < 5; i++){
    int idx = tid + i*512;
    int r = idx / 40;
    int c = idx - r*40;
    int node = n0 + r;
    uint4 v = (node < NN) ? *(const uint4*)(agg + (size_t)node*NFD + c*8)
                          : make_uint4(0,0,0,0);
    *(uint4*)(s_b + r*328 + c*8) = v;
  }
  __syncthreads();

  // ---- n1 half1 (agg part): ks 10..19 ----
  gemm5(s_b, Wn1p, arow0, arow1, kl, ch*100 + 10, 20, lane, acc);
  __syncthreads();               // all waves done reading agg

  // ---- hid = silu(n1) -> s_b (overwrite, d16hi trick) ----
  #pragma unroll
  for (int t = 0; t < 5; t++){
    int o = (ch*5 + t)*16 + (lane & 15);
    float bb = bn1[o];
    #pragma unroll
    for (int r = 0; r < 4; r++){
      float v0 = silu_f(acc[0][t][r] + bb);
      float v1 = silu_f(acc[1][t][r] + bb);
      unsigned int q = cvt_pk_bf16(v0, v1);
      int er = rh*32 + rb + r;
      s_b[er*328 + o] = (unsigned short)q;
      s_b[(er+16)*328 + o] = (unsigned short)(q >> 16);
    }
  }
  __syncthreads();

  // ---- n2: out = hid @ Wn2^T + bn2 + h (residual) ----
  #pragma unroll
  for (int rt = 0; rt < 2; rt++)
    #pragma unroll
    for (int t = 0; t < 5; t++) acc[rt][t] = {0.f,0.f,0.f,0.f};
  gemm5(s_b, Wn2p, arow0, arow1, kl, ch*50, 10, lane, acc);
  #pragma unroll
  for (int t = 0; t < 5; t++){
    int o = (ch*5 + t)*16 + (lane & 15);
    float bb = bn2[o];
    #pragma unroll
    for (int r = 0; r < 4; r++){
      int node0 = n0 + rh*32 + rb + r;
      int node1 = node0 + 16;
      if (node0 < NN)
        hout[(size_t)node0*NFD + o] = h[(size_t)node0*NFD + o] + acc[0][t][r] + bb;
      if (node1 < NN)
        hout[(size_t)node1*NFD + o] = h[(size_t)node1*NFD + o] + acc[1][t][r] + bb;
    }
  }
}

extern "C" void kernel_launch(void* const* d_in, const int* in_sizes, int n_in,
                              void* d_out, int out_size, void* d_ws, size_t ws_size,
                              hipStream_t stream){
  const float* h     = (const float*)d_in[0];
  const float* coord = (const float*)d_in[1];
  const int*   ei    = (const int*)d_in[2];
  const float* We1 = (const float*)d_in[3];
  const float* be1 = (const float*)d_in[4];
  const float* We2 = (const float*)d_in[5];
  const float* be2 = (const float*)d_in[6];
  const float* Wn1 = (const float*)d_in[7];
  const float* bn1 = (const float*)d_in[8];
  const float* Wn2 = (const float*)d_in[9];
  const float* bn2 = (const float*)d_in[10];
  const float* Wc1 = (const float*)d_in[11];
  const float* bc1 = (const float*)d_in[12];
  const float* Wc2 = (const float*)d_in[13];

  char* ws = (char*)d_ws;
  unsigned short* We2p = (unsigned short*)(ws);             // 204800
  unsigned short* Wc1p = (unsigned short*)(ws + 204800);    // 204800
  unsigned short* Wn1p = (unsigned short*)(ws + 409600);    // 409600
  unsigned short* Wn2p = (unsigned short*)(ws + 819200);    // 204800
  unsigned short* Wsp  = (unsigned short*)(ws + 1024000);   // 409600
  float*          we1l = (float*)(ws + 1433600);            // 1280
  unsigned short* agg  = (unsigned short*)(ws + 1434880);   // 32,000,000
  int*            cnt  = (int*)(ws + 33434880);             // 200,000
  int*            cur  = (int*)(ws + 33634880);             // 200,000
  int*            perm = (int*)(ws + 33834880);             // 1,600,000
  int*            bsum = (int*)(ws + 35434880);             // 1,024

  float* hout = (float*)d_out;
  float* cout = hout + (size_t)NN * NFD;        // coord output region
  unsigned short* Pbf = (unsigned short*)d_out; // P in dead hout region (64 MB)

  hipMemsetAsync(agg, 0, (size_t)NN * NFD * 2, stream);
  hipMemsetAsync(cnt, 0, (size_t)NN * 4, stream);

  prep_k<<<PREP_PACK_B + PREP_CIN_B + PREP_HIST_B, 512, 0, stream>>>(
      We2, Wc1, Wn1, Wn2, We1, We2p, Wc1p, Wn1p, Wn2p, Wsp, we1l,
      coord, cout, ei, cnt);

  scan1<<<NB1, 256, 0, stream>>>(cnt, cur, bsum);
  scan2<<<1, 256, 0, stream>>>(bsum);
  scan3<<<NB1, 256, 0, stream>>>(cur, bsum);

  scat_pre<<<SP_SCAT_B + (NN + 31)/32, 512, 0, stream>>>(
      ei, cur, perm, h, Wsp, be1, Pbf);

  edge_kernel<<<EDGE_NWG, 256, 0, stream>>>(Pbf, coord, ei, perm, we1l,
                                            We2p, be2, Wc1p, bc1, Wc2, agg, cout);
  node_kernel<<<(NN + 63)/64, 512, 0, stream>>>(h, agg, Wn1p, bn1, Wn2p, bn2, hout);
}